// Round 9
// baseline (4079.092 us; speedup 1.0000x reference)
//
#include <hip/hip_runtime.h>

#define NN    60000
#define NODES 100000
#define DD    64
#define NNZ   3200000
#define BB    1024
#define NEG   0.2f
#define RPB   196                        // rows per bucket
#define NBUCK 511                        // ceil(NODES/RPB); 511 = 2*256-1 -> all co-resident
#define EPB   8192                       // edges per sort block
#define NPB   ((NNZ + EPB - 1) / EPB)    // 391
#define CAP   7000                       // bucket capacity (mean 6272, sd~79)
#define BCAP  7168                       // LDS edge capacity in k_csr
#define NSEG  13                         // column segments (col>>13), ~2 MB x-slice each
#define KEYN  (NSEG * RPB)               // 2548 sort keys per bucket
#define SPB   (KEYN + 1)                 // starts entries per bucket

// ---------------------------------------------------------------- init x = concat(eu, ei); also init gcur
__global__ __launch_bounds__(256) void k_init_x(const float* __restrict__ eu,
                                                const float* __restrict__ ei,
                                                float* __restrict__ x,
                                                int* __restrict__ gcur) {
    int i = blockIdx.x * 256 + threadIdx.x;          // float4 index
    if (i < NBUCK) gcur[i] = i * CAP;
    const int TOT = NODES * DD / 4;
    if (i >= TOT) return;
    const int UE = NN * DD / 4;
    float4 v = (i < UE) ? ((const float4*)eu)[i] : ((const float4*)ei)[i - UE];
    ((float4*)x)[i] = v;
}

// ---------------------------------------------------------------- bucket sort -> bulk
__global__ __launch_bounds__(512) void k_place(const int* __restrict__ row,
                                               const int* __restrict__ col,
                                               const float* __restrict__ val,
                                               int* __restrict__ gcur,
                                               int2* __restrict__ bulk) {
    __shared__ int rows_l[EPB];                // 32 KB
    __shared__ unsigned short perm[EPB];       // 16 KB
    __shared__ int h[NBUCK], bloc[NBUCK], bcur[NBUCK], gseg[NBUCK];
    __shared__ int sc[512];
    int t = threadIdx.x;
    if (t < NBUCK) h[t] = 0;
    __syncthreads();
    int base = blockIdx.x * EPB;
    int n = min(EPB, NNZ - base);
    for (int k = t; k < n; k += 512) {
        int r = row[base + k];
        rows_l[k] = r;
        atomicAdd(&h[r / RPB], 1);
    }
    __syncthreads();
    {
        int v = (t < NBUCK) ? h[t] : 0;
        sc[t] = v;
        __syncthreads();
        for (int off = 1; off < 512; off <<= 1) {
            int u = (t >= off) ? sc[t - off] : 0;
            __syncthreads();
            sc[t] += u;
            __syncthreads();
        }
        if (t < NBUCK) {
            int ex = sc[t] - v;
            bloc[t] = ex;
            bcur[t] = ex;
            gseg[t] = v ? atomicAdd(&gcur[t], v) : 0;
        }
    }
    __syncthreads();
    for (int k = t; k < n; k += 512) {
        int p = atomicAdd(&bcur[rows_l[k] / RPB], 1);
        perm[p] = (unsigned short)k;
    }
    __syncthreads();
    for (int j = t; j < n; j += 512) {
        int k = perm[j];
        int r = rows_l[k];
        int b = r / RPB;
        int addr = gseg[b] + (j - bloc[b]);
        bulk[addr] = make_int2(((r - b * RPB) << 17) | col[base + k],
                               __float_as_int(val[base + k]));
    }
}

// ---------------------------------------------------------------- per-bucket (colseg,row) sort
// in-place (keeps packed local-row bits); emit per-key span starts + sentinel
__global__ __launch_bounds__(512) void k_csr(const int* __restrict__ gcur,
                                             int2* __restrict__ bulk,
                                             int* __restrict__ starts) {
    __shared__ int2 eds[BCAP];                 // 56 KB
    __shared__ int cnt[KEYN], pos[KEYN];       // 20 KB
    __shared__ int part[512];
    int b = blockIdx.x, t = threadIdx.x;
    int lo = b * CAP;
    int n = gcur[b] - lo;
    for (int k = t; k < KEYN; k += 512) cnt[k] = 0;
    __syncthreads();
    for (int i = t; i < n; i += 512) {
        int2 ed = bulk[lo + i];
        eds[i] = ed;
        int lr = ed.x >> 17, c = ed.x & 0x1FFFF;
        atomicAdd(&cnt[(c >> 13) * RPB + lr], 1);
    }
    __syncthreads();
    // two-level exclusive scan over KEYN bins (5 bins/thread)
    int run = 0;
#pragma unroll
    for (int j = 0; j < 5; ++j) {
        int k = t * 5 + j;
        if (k < KEYN) { pos[k] = run; run += cnt[k]; }
    }
    part[t] = run;
    __syncthreads();
    for (int off = 1; off < 512; off <<= 1) {
        int u = (t >= off) ? part[t - off] : 0;
        __syncthreads();
        part[t] += u;
        __syncthreads();
    }
    int poff = part[t] - run;
#pragma unroll
    for (int j = 0; j < 5; ++j) {
        int k = t * 5 + j;
        if (k < KEYN) pos[k] += poff;
    }
    __syncthreads();
    for (int k = t; k < KEYN; k += 512) {
        starts[b * SPB + k] = lo + pos[k];
        cnt[k] = pos[k];                      // reuse as cursor
    }
    if (t == 0) starts[b * SPB + KEYN] = lo + n;
    __syncthreads();
    for (int i = t; i < n; i += 512) {
        int2 ed = eds[i];
        int lr = ed.x >> 17, c = ed.x & 0x1FFFF;
        int p = atomicAdd(&cnt[(c >> 13) * RPB + lr], 1);
        bulk[lo + p] = ed;                    // keep packed (lr<<17 | col)
    }
}

// ---------------------------------------------------------------- fused convoyed SpMM + GEMM layer
// Phase S: convoyed seg-major pull SpMM into LDS acc (== lie for this bucket)
// Phase A: o  = b1+b2 + acc@W1       (register 4row x 4col tiles, W from L1)
// Phase B: acc *= xin[own rows]      (elementwise)
// Phase C: o += acc@W2; leaky; write xout (ping-pong; xin still read by others)
__global__ __launch_bounds__(1024, 8) void k_cspmm(const int* __restrict__ starts,
                                                   const int2* __restrict__ cv,
                                                   const float* __restrict__ xin,
                                                   float* __restrict__ xout,
                                                   const float* __restrict__ W1,
                                                   const float* __restrict__ W2,
                                                   const float* __restrict__ b1,
                                                   const float* __restrict__ b2) {
    __shared__ float acc[RPB * DD];            // 49 KB
    int t = threadIdx.x, b = blockIdx.x;
    float4* av = (float4*)acc;
    for (int i = t; i < RPB * 16; i += 1024) av[i] = make_float4(0.f, 0.f, 0.f, 0.f);
    __syncthreads();
    // ---------------- Phase S: SpMM ----------------
    {
        int wid = t >> 6, lane = t & 63;
        int r0 = (wid * RPB) >> 4;
        int r1 = ((wid + 1) * RPB) >> 4;
        int sb = b * SPB;
        for (int seg = 0; seg < NSEG; ++seg) {
            int s = starts[sb + seg * RPB + r0];
            int e = starts[sb + seg * RPB + r1];
            int cur = -1;
            float f = 0.f;
            int g = s;
            for (; g + 8 <= e; g += 8) {
                int2 ee[8];
#pragma unroll
                for (int j = 0; j < 8; ++j) ee[j] = cv[g + j];
                float xv[8];
#pragma unroll
                for (int j = 0; j < 8; ++j) xv[j] = xin[(ee[j].x & 0x1FFFF) * DD + lane];
#pragma unroll
                for (int j = 0; j < 8; ++j) {
                    int r = ee[j].x >> 17;
                    if (r != cur) {                 // wave-uniform branch
                        if (cur >= 0) acc[cur * DD + lane] += f;
                        cur = r; f = 0.f;
                    }
                    f = fmaf(__int_as_float(ee[j].y), xv[j], f);
                }
            }
            for (; g < e; ++g) {
                int2 ed = cv[g];
                float xg = xin[(ed.x & 0x1FFFF) * DD + lane];
                int r = ed.x >> 17;
                if (r != cur) {
                    if (cur >= 0) acc[cur * DD + lane] += f;
                    cur = r; f = 0.f;
                }
                f = fmaf(__int_as_float(ed.y), xg, f);
            }
            if (cur >= 0) acc[cur * DD + lane] += f;
        }
    }
    __syncthreads();
    // ---------------- epilogue GEMM ----------------
    const int tx = t & 15;        // 4-col group
    const int r00 = t >> 4;       // row slot, stride 64 (q = 0..3)
    const int row0 = b * RPB;
    float4 o[4];
    {
        float4 bb1 = *(const float4*)&b1[tx * 4];
        float4 bb2 = *(const float4*)&b2[tx * 4];
        float4 bs = make_float4(bb1.x + bb2.x, bb1.y + bb2.y,
                                bb1.z + bb2.z, bb1.w + bb2.w);
#pragma unroll
        for (int q = 0; q < 4; ++q) o[q] = bs;
    }
    // Phase A: o += acc @ W1
    for (int k4 = 0; k4 < 16; ++k4) {
        float4 a[4];
#pragma unroll
        for (int q = 0; q < 4; ++q) {
            int rr = r00 + 64 * q;
            a[q] = (rr < RPB) ? av[rr * 16 + k4] : make_float4(0.f, 0.f, 0.f, 0.f);
        }
#pragma unroll
        for (int kk = 0; kk < 4; ++kk) {
            float4 w = *(const float4*)&W1[(k4 * 4 + kk) * 64 + tx * 4];
#pragma unroll
            for (int q = 0; q < 4; ++q) {
                float aq = (&a[q].x)[kk];
                o[q].x = fmaf(aq, w.x, o[q].x);
                o[q].y = fmaf(aq, w.y, o[q].y);
                o[q].z = fmaf(aq, w.z, o[q].z);
                o[q].w = fmaf(aq, w.w, o[q].w);
            }
        }
    }
    __syncthreads();
    // Phase B: acc *= xin[own rows]
    for (int i = t; i < RPB * 16; i += 1024) {
        int gr = row0 + (i >> 4);
        float4 xv = (gr < NODES) ? ((const float4*)xin)[gr * 16 + (i & 15)]
                                 : make_float4(0.f, 0.f, 0.f, 0.f);
        float4 a = av[i];
        av[i] = make_float4(a.x * xv.x, a.y * xv.y, a.z * xv.z, a.w * xv.w);
    }
    __syncthreads();
    // Phase C: o += acc @ W2; leaky relu; store
    for (int k4 = 0; k4 < 16; ++k4) {
        float4 a[4];
#pragma unroll
        for (int q = 0; q < 4; ++q) {
            int rr = r00 + 64 * q;
            a[q] = (rr < RPB) ? av[rr * 16 + k4] : make_float4(0.f, 0.f, 0.f, 0.f);
        }
#pragma unroll
        for (int kk = 0; kk < 4; ++kk) {
            float4 w = *(const float4*)&W2[(k4 * 4 + kk) * 64 + tx * 4];
#pragma unroll
            for (int q = 0; q < 4; ++q) {
                float aq = (&a[q].x)[kk];
                o[q].x = fmaf(aq, w.x, o[q].x);
                o[q].y = fmaf(aq, w.y, o[q].y);
                o[q].z = fmaf(aq, w.z, o[q].z);
                o[q].w = fmaf(aq, w.w, o[q].w);
            }
        }
    }
#pragma unroll
    for (int q = 0; q < 4; ++q) {
        int rr = r00 + 64 * q;
        int gr = row0 + rr;
        if (rr < RPB && gr < NODES) {
            float4 v;
            v.x = o[q].x >= 0.f ? o[q].x : NEG * o[q].x;
            v.y = o[q].y >= 0.f ? o[q].y : NEG * o[q].y;
            v.z = o[q].z >= 0.f ? o[q].z : NEG * o[q].z;
            v.w = o[q].w >= 0.f ? o[q].w : NEG * o[q].w;
            ((float4*)xout)[gr * 16 + tx] = v;
        }
    }
}

// ---------------------------------------------------------------- gather layer repr into output
__global__ __launch_bounds__(256) void k_gather(const float* __restrict__ x,
                                                const int* __restrict__ su,
                                                const int* __restrict__ oi,
                                                const int* __restrict__ ui,
                                                float* __restrict__ out, int layer) {
    int w    = (blockIdx.x * 256 + threadIdx.x) >> 6;
    int lane = threadIdx.x & 63;
    if (w >= 3 * BB) return;
    int g = w >> 10, b = w & 1023;
    int node = (g == 0) ? su[b] : (NN + ((g == 1) ? oi[b] : ui[b]));
    out[w * 256 + layer * 64 + lane] = x[node * DD + lane];
}

// ---------------------------------------------------------------- launch
extern "C" void kernel_launch(void* const* d_in, const int* in_sizes, int n_in,
                              void* d_out, int out_size, void* d_ws, size_t ws_size,
                              hipStream_t stream) {
    const int*   edge_row = (const int*)d_in[0];
    const int*   edge_col = (const int*)d_in[1];
    const float* edge_val = (const float*)d_in[2];
    const float* eu = (const float*)d_in[3];
    const float* ei = (const float*)d_in[4];
    const float* W1 = (const float*)d_in[5];
    const float* W2 = (const float*)d_in[6];
    const float* b1 = (const float*)d_in[7];
    const float* b2 = (const float*)d_in[8];
    const int*   su = (const int*)d_in[9];
    const int*   oi = (const int*)d_in[10];
    const int*   ui = (const int*)d_in[11];
    float* out = (float*)d_out;

    // workspace carve (~85 MB)
    float* xA     = (float*)d_ws;                    // 25.6 MB
    float* xB     = xA + NODES * DD;                 // 25.6 MB (ping-pong)
    int2*  bulk   = (int2*)(xB + NODES * DD);        // NBUCK*CAP int2 (28.6 MB)
    int*   gcur   = (int*)(bulk + NBUCK * CAP);      // NBUCK
    int*   starts = gcur + NBUCK + 1;                // NBUCK*SPB (5.2 MB)

    k_init_x<<<(NODES * DD / 4 + 255) / 256, 256, 0, stream>>>(eu, ei, xA, gcur);
    k_gather<<<(3 * BB * 64 + 255) / 256, 256, 0, stream>>>(xA, su, oi, ui, out, 0);

    k_place<<<NPB, 512, 0, stream>>>(edge_row, edge_col, edge_val, gcur, bulk);
    k_csr<<<NBUCK, 512, 0, stream>>>(gcur, bulk, starts);

    const float* xi = xA;
    float*       xo = xB;
    for (int l = 0; l < 3; ++l) {
        k_cspmm<<<NBUCK, 1024, 0, stream>>>(starts, bulk, xi, xo,
                                            W1 + l * 4096, W2 + l * 4096,
                                            b1 + l * 64,  b2 + l * 64);
        k_gather<<<(3 * BB * 64 + 255) / 256, 256, 0, stream>>>(xo, su, oi, ui, out, l + 1);
        const float* tmp = xo; xo = (float*)xi; xi = tmp;
    }
}

// Round 10
// 665.600 us; speedup vs baseline: 6.1284x; 6.1284x over previous
//
#include <hip/hip_runtime.h>

#define NN    60000
#define NODES 100000
#define DD    64
#define NNZ   3200000
#define BB    1024
#define NEG   0.2f
#define RPB   196                        // rows per bucket
#define NBUCK 511                        // ceil(NODES/RPB); 511 -> all co-resident at 2/CU
#define EPB   8192                       // edges per sort block
#define NPB   ((NNZ + EPB - 1) / EPB)    // 391
#define CAP   7000                       // bucket capacity (mean 6272, sd~79)
#define BCAP  7168                       // LDS edge capacity in k_csr
#define NSEG  13                         // column segments (col>>13), ~2 MB x-slice each
#define KEYN  (NSEG * RPB)               // 2548 sort keys per bucket
#define SPB   (KEYN + 1)                 // starts entries per bucket

// ---------------------------------------------------------------- init x = concat(eu, ei); also init gcur
__global__ __launch_bounds__(256) void k_init_x(const float* __restrict__ eu,
                                                const float* __restrict__ ei,
                                                float* __restrict__ x,
                                                int* __restrict__ gcur) {
    int i = blockIdx.x * 256 + threadIdx.x;          // float4 index
    if (i < NBUCK) gcur[i] = i * CAP;
    const int TOT = NODES * DD / 4;
    if (i >= TOT) return;
    const int UE = NN * DD / 4;
    float4 v = (i < UE) ? ((const float4*)eu)[i] : ((const float4*)ei)[i - UE];
    ((float4*)x)[i] = v;
}

// ---------------------------------------------------------------- bucket sort -> bulk
__global__ __launch_bounds__(512) void k_place(const int* __restrict__ row,
                                               const int* __restrict__ col,
                                               const float* __restrict__ val,
                                               int* __restrict__ gcur,
                                               int2* __restrict__ bulk) {
    __shared__ int rows_l[EPB];                // 32 KB
    __shared__ unsigned short perm[EPB];       // 16 KB
    __shared__ int h[NBUCK], bloc[NBUCK], bcur[NBUCK], gseg[NBUCK];
    __shared__ int sc[512];
    int t = threadIdx.x;
    if (t < NBUCK) h[t] = 0;
    __syncthreads();
    int base = blockIdx.x * EPB;
    int n = min(EPB, NNZ - base);
    for (int k = t; k < n; k += 512) {
        int r = row[base + k];
        rows_l[k] = r;
        atomicAdd(&h[r / RPB], 1);
    }
    __syncthreads();
    {
        int v = (t < NBUCK) ? h[t] : 0;
        sc[t] = v;
        __syncthreads();
        for (int off = 1; off < 512; off <<= 1) {
            int u = (t >= off) ? sc[t - off] : 0;
            __syncthreads();
            sc[t] += u;
            __syncthreads();
        }
        if (t < NBUCK) {
            int ex = sc[t] - v;
            bloc[t] = ex;
            bcur[t] = ex;
            gseg[t] = v ? atomicAdd(&gcur[t], v) : 0;
        }
    }
    __syncthreads();
    for (int k = t; k < n; k += 512) {
        int p = atomicAdd(&bcur[rows_l[k] / RPB], 1);
        perm[p] = (unsigned short)k;
    }
    __syncthreads();
    for (int j = t; j < n; j += 512) {
        int k = perm[j];
        int r = rows_l[k];
        int b = r / RPB;
        int addr = gseg[b] + (j - bloc[b]);
        bulk[addr] = make_int2(((r - b * RPB) << 17) | col[base + k],
                               __float_as_int(val[base + k]));
    }
}

// ---------------------------------------------------------------- per-bucket (colseg,row) sort
// in-place (keeps packed local-row bits); emit per-key span starts + sentinel
__global__ __launch_bounds__(512) void k_csr(const int* __restrict__ gcur,
                                             int2* __restrict__ bulk,
                                             int* __restrict__ starts) {
    __shared__ int2 eds[BCAP];                 // 56 KB
    __shared__ int cnt[KEYN], pos[KEYN];       // 20 KB
    __shared__ int part[512];
    int b = blockIdx.x, t = threadIdx.x;
    int lo = b * CAP;
    int n = gcur[b] - lo;
    for (int k = t; k < KEYN; k += 512) cnt[k] = 0;
    __syncthreads();
    for (int i = t; i < n; i += 512) {
        int2 ed = bulk[lo + i];
        eds[i] = ed;
        int lr = ed.x >> 17, c = ed.x & 0x1FFFF;
        atomicAdd(&cnt[(c >> 13) * RPB + lr], 1);
    }
    __syncthreads();
    // two-level exclusive scan over KEYN bins (5 bins/thread)
    int run = 0;
#pragma unroll
    for (int j = 0; j < 5; ++j) {
        int k = t * 5 + j;
        if (k < KEYN) { pos[k] = run; run += cnt[k]; }
    }
    part[t] = run;
    __syncthreads();
    for (int off = 1; off < 512; off <<= 1) {
        int u = (t >= off) ? part[t - off] : 0;
        __syncthreads();
        part[t] += u;
        __syncthreads();
    }
    int poff = part[t] - run;
#pragma unroll
    for (int j = 0; j < 5; ++j) {
        int k = t * 5 + j;
        if (k < KEYN) pos[k] += poff;
    }
    __syncthreads();
    for (int k = t; k < KEYN; k += 512) {
        starts[b * SPB + k] = lo + pos[k];
        cnt[k] = pos[k];                      // reuse as cursor
    }
    if (t == 0) starts[b * SPB + KEYN] = lo + n;
    __syncthreads();
    for (int i = t; i < n; i += 512) {
        int2 ed = eds[i];
        int lr = ed.x >> 17, c = ed.x & 0x1FFFF;
        int p = atomicAdd(&cnt[(c >> 13) * RPB + lr], 1);
        bulk[lo + p] = ed;                    // keep packed (lr<<17 | col)
    }
}

// ---------------------------------------------------------------- fused convoyed SpMM + GEMM layer
// Phase S: convoyed seg-major pull SpMM into LDS acc (== lie for this bucket).
// Epilogue (register-lean, lane = output column):
//   wave reads W rows once per (k4,kk) (coalesced, L1-hot) and reuses across
//   its rows; acc/xin read as wave-uniform broadcasts; o[row] scalar per lane.
//   xout = leaky(b1+b2 + lie@W1 + (x*lie)@W2), ping-pong buffer.
__global__ __launch_bounds__(1024) void k_cspmm(const int* __restrict__ starts,
                                                const int2* __restrict__ cv,
                                                const float* __restrict__ xin,
                                                float* __restrict__ xout,
                                                const float* __restrict__ W1,
                                                const float* __restrict__ W2,
                                                const float* __restrict__ b1,
                                                const float* __restrict__ b2) {
    __shared__ float acc[RPB * DD];            // 49 KB
    int t = threadIdx.x, b = blockIdx.x;
    float4* av = (float4*)acc;
    for (int i = t; i < RPB * 16; i += 1024) av[i] = make_float4(0.f, 0.f, 0.f, 0.f);
    __syncthreads();
    const int wid = t >> 6, lane = t & 63;
    const int r0 = (wid * RPB) >> 4;
    const int r1 = ((wid + 1) * RPB) >> 4;
    // ---------------- Phase S: SpMM ----------------
    {
        int sb = b * SPB;
        for (int seg = 0; seg < NSEG; ++seg) {
            int s = starts[sb + seg * RPB + r0];
            int e = starts[sb + seg * RPB + r1];
            int cur = -1;
            float f = 0.f;
            int g = s;
            for (; g + 8 <= e; g += 8) {
                int2 ee[8];
#pragma unroll
                for (int j = 0; j < 8; ++j) ee[j] = cv[g + j];
                float xv[8];
#pragma unroll
                for (int j = 0; j < 8; ++j) xv[j] = xin[(ee[j].x & 0x1FFFF) * DD + lane];
#pragma unroll
                for (int j = 0; j < 8; ++j) {
                    int r = ee[j].x >> 17;
                    if (r != cur) {                 // wave-uniform branch
                        if (cur >= 0) acc[cur * DD + lane] += f;
                        cur = r; f = 0.f;
                    }
                    f = fmaf(__int_as_float(ee[j].y), xv[j], f);
                }
            }
            for (; g < e; ++g) {
                int2 ed = cv[g];
                float xg = xin[(ed.x & 0x1FFFF) * DD + lane];
                int r = ed.x >> 17;
                if (r != cur) {
                    if (cur >= 0) acc[cur * DD + lane] += f;
                    cur = r; f = 0.f;
                }
                f = fmaf(__int_as_float(ed.y), xg, f);
            }
            if (cur >= 0) acc[cur * DD + lane] += f;
        }
    }
    __syncthreads();
    // ---------------- epilogue GEMM ----------------
    const int row0 = b * RPB;
    const int nr = r1 - r0;                    // 12 or 13
    float bias = b1[lane] + b2[lane];
    float o[13];
#pragma unroll
    for (int i = 0; i < 13; ++i) o[i] = bias;
    for (int k4 = 0; k4 < 16; ++k4) {
        float w1r[4], w2r[4];
#pragma unroll
        for (int kk = 0; kk < 4; ++kk) {
            w1r[kk] = W1[(k4 * 4 + kk) * DD + lane];
            w2r[kk] = W2[(k4 * 4 + kk) * DD + lane];
        }
#pragma unroll
        for (int i = 0; i < 13; ++i) {
            if (i >= nr) break;                // wave-uniform
            int r = r0 + i;
            int gr = row0 + r;
            float4 a = *(const float4*)&acc[r * DD + k4 * 4];          // LDS broadcast
            float4 xv = (gr < NODES) ? ((const float4*)xin)[gr * 16 + k4]
                                     : make_float4(0.f, 0.f, 0.f, 0.f); // L1 broadcast
            float oi = o[i];
            oi = fmaf(a.x, w1r[0], oi);
            oi = fmaf(a.y, w1r[1], oi);
            oi = fmaf(a.z, w1r[2], oi);
            oi = fmaf(a.w, w1r[3], oi);
            oi = fmaf(a.x * xv.x, w2r[0], oi);
            oi = fmaf(a.y * xv.y, w2r[1], oi);
            oi = fmaf(a.z * xv.z, w2r[2], oi);
            oi = fmaf(a.w * xv.w, w2r[3], oi);
            o[i] = oi;
        }
    }
#pragma unroll
    for (int i = 0; i < 13; ++i) {
        if (i >= nr) break;
        int gr = row0 + r0 + i;
        if (gr < NODES) {
            float v = o[i];
            xout[gr * DD + lane] = v >= 0.f ? v : NEG * v;
        }
    }
}

// ---------------------------------------------------------------- gather layer repr into output
__global__ __launch_bounds__(256) void k_gather(const float* __restrict__ x,
                                                const int* __restrict__ su,
                                                const int* __restrict__ oi,
                                                const int* __restrict__ ui,
                                                float* __restrict__ out, int layer) {
    int w    = (blockIdx.x * 256 + threadIdx.x) >> 6;
    int lane = threadIdx.x & 63;
    if (w >= 3 * BB) return;
    int g = w >> 10, b = w & 1023;
    int node = (g == 0) ? su[b] : (NN + ((g == 1) ? oi[b] : ui[b]));
    out[w * 256 + layer * 64 + lane] = x[node * DD + lane];
}

// ---------------------------------------------------------------- launch
extern "C" void kernel_launch(void* const* d_in, const int* in_sizes, int n_in,
                              void* d_out, int out_size, void* d_ws, size_t ws_size,
                              hipStream_t stream) {
    const int*   edge_row = (const int*)d_in[0];
    const int*   edge_col = (const int*)d_in[1];
    const float* edge_val = (const float*)d_in[2];
    const float* eu = (const float*)d_in[3];
    const float* ei = (const float*)d_in[4];
    const float* W1 = (const float*)d_in[5];
    const float* W2 = (const float*)d_in[6];
    const float* b1 = (const float*)d_in[7];
    const float* b2 = (const float*)d_in[8];
    const int*   su = (const int*)d_in[9];
    const int*   oi = (const int*)d_in[10];
    const int*   ui = (const int*)d_in[11];
    float* out = (float*)d_out;

    // workspace carve (~85 MB)
    float* xA     = (float*)d_ws;                    // 25.6 MB
    float* xB     = xA + NODES * DD;                 // 25.6 MB (ping-pong)
    int2*  bulk   = (int2*)(xB + NODES * DD);        // NBUCK*CAP int2 (28.6 MB)
    int*   gcur   = (int*)(bulk + NBUCK * CAP);      // NBUCK
    int*   starts = gcur + NBUCK + 1;                // NBUCK*SPB (5.2 MB)

    k_init_x<<<(NODES * DD / 4 + 255) / 256, 256, 0, stream>>>(eu, ei, xA, gcur);
    k_gather<<<(3 * BB * 64 + 255) / 256, 256, 0, stream>>>(xA, su, oi, ui, out, 0);

    k_place<<<NPB, 512, 0, stream>>>(edge_row, edge_col, edge_val, gcur, bulk);
    k_csr<<<NBUCK, 512, 0, stream>>>(gcur, bulk, starts);

    const float* xi = xA;
    float*       xo = xB;
    for (int l = 0; l < 3; ++l) {
        k_cspmm<<<NBUCK, 1024, 0, stream>>>(starts, bulk, xi, xo,
                                            W1 + l * 4096, W2 + l * 4096,
                                            b1 + l * 64,  b2 + l * 64);
        k_gather<<<(3 * BB * 64 + 255) / 256, 256, 0, stream>>>(xo, su, oi, ui, out, l + 1);
        const float* tmp = xo; xo = (float*)xi; xi = tmp;
    }
}